// Round 8
// baseline (120.518 us; speedup 1.0000x reference)
//
#include <hip/hip_runtime.h>

// Fused 3-layer MLP via MFMA with split-bf16 (hi+lo) 3-term products:
//   out = relu(relu(x@W0+b0)@W1+b1)@W2+b2
// x: [N,128] f32, W0:[128,32], W1:[32,32], W2:[32,16], out:[N,16] f32.
// edge_index/edge_weight unused (ChebConv K=1).
//
// R8 = R7 structure (weights in LDS, persistent grid, barrier-free loop,
// nt loads/stores) + ONE change: 32-node wave-tile (two 16-row MFMA
// A-blocks per tile sharing one weight-fragment read stream).
//  - weight ds_reads per node halved (22 per 32 nodes, was 22 per 16)
//  - layer-1/2 W reads, hbuf traffic amortized over 2x bytes
//  - launch_bounds(256,3) (VGPR cap 168; R5/R6 showed spills at the
//    128-cap kill perf) and 768 persistent blocks = 3 blocks/CU resident.
//
// MFMA frag layouts (m89-verified):
//  A: lane l holds A[l&15][8*(l>>4)+j], j=0..7
//  B: lane l holds B[8*(l>>4)+j][l&15]
//  C/D: lane l holds D[4*(l>>4)+i][l&15], i=0..3
// Split: v = hi + lo, hi = trunc-to-bf16 (bit mask, exact),
// lo = rne-bf16(v - hi); product = ah*bh + al*bh + ah*bl (~f32 accuracy).

#define N_IN  128
#define HID   32
#define N_OUT 16

using f32x4  = __attribute__((ext_vector_type(4))) float;
using short8 = __attribute__((ext_vector_type(8))) short;
using uint4v = __attribute__((ext_vector_type(4))) unsigned int;

// chunk layout in ws (each chunk = 64 lanes * 8 bf16 = 512 shorts = 1KB):
//  W0: chunks [0,16): chunk = kc*4 + nh*2 + hl   (kc=0..3, nh=0..1, hl=0..1)
//  W1: chunks [16,20): 16 + nh*2 + hl
//  W2: chunks [20,22): 20 + hl
#define N_CHUNKS 22
#define TOTAL_WF_SHORTS (N_CHUNKS * 512)
#define WLDS_GRANULES (N_CHUNKS * 64)   // 16B granules

__device__ __forceinline__ unsigned fu(float f) {
    union { float f; unsigned u; } v; v.f = f; return v.u;
}
__device__ __forceinline__ float uf(unsigned u) {
    union { unsigned u; float f; } v; v.u = u; return v.f;
}
__device__ __forceinline__ unsigned short f2bf_rne(float f) {
    unsigned u = fu(f);
    return (unsigned short)((u + 0x7fffu + ((u >> 16) & 1u)) >> 16);
}

__global__ void split_weights(const float* __restrict__ W0,
                              const float* __restrict__ W1,
                              const float* __restrict__ W2,
                              unsigned short* __restrict__ wf) {
    int idx = blockIdx.x * blockDim.x + threadIdx.x;
    if (idx >= TOTAL_WF_SHORTS) return;
    int chunk  = idx >> 9;
    int within = idx & 511;
    int lane = within >> 3;
    int j    = within & 7;
    const float* W; int ncol, k, col, hl;
    if (chunk < 16) {
        int kc = chunk >> 2, nh = (chunk >> 1) & 1; hl = chunk & 1;
        k = kc * 32 + 8 * (lane >> 4) + j; col = nh * 16 + (lane & 15);
        W = W0; ncol = HID;
    } else if (chunk < 20) {
        int c2 = chunk - 16, nh = c2 >> 1; hl = c2 & 1;
        k = 8 * (lane >> 4) + j; col = nh * 16 + (lane & 15);
        W = W1; ncol = HID;
    } else {
        hl = chunk - 20;
        k = 8 * (lane >> 4) + j; col = lane & 15;
        W = W2; ncol = N_OUT;
    }
    float v = W[k * ncol + col];
    unsigned hi_bits = fu(v) & 0xFFFF0000u;
    wf[idx] = (hl == 0) ? (unsigned short)(hi_bits >> 16)
                        : f2bf_rne(v - uf(hi_bits));
}

#define MFMA3(acc, ah, al, bh, bl)                                          \
    do {                                                                    \
        acc = __builtin_amdgcn_mfma_f32_16x16x32_bf16(ah, bh, acc, 0, 0, 0);\
        acc = __builtin_amdgcn_mfma_f32_16x16x32_bf16(al, bh, acc, 0, 0, 0);\
        acc = __builtin_amdgcn_mfma_f32_16x16x32_bf16(ah, bl, acc, 0, 0, 0);\
    } while (0)

// split 8 f32 (two f32x4) into bf16 hi/lo fragments
#define SPLIT8(xa, xb, AH, AL)                                              \
    do {                                                                    \
        float f_[8] = {(xa)[0], (xa)[1], (xa)[2], (xa)[3],                  \
                       (xb)[0], (xb)[1], (xb)[2], (xb)[3]};                 \
        uint4v hv_, lv_;                                                    \
        _Pragma("unroll")                                                   \
        for (int p_ = 0; p_ < 4; ++p_) {                                    \
            unsigned u0_ = fu(f_[2 * p_]), u1_ = fu(f_[2 * p_ + 1]);        \
            unsigned h0_ = u0_ & 0xFFFF0000u, h1_ = u1_ & 0xFFFF0000u;      \
            hv_[p_] = h1_ | (u0_ >> 16);                                    \
            float l0_ = f_[2 * p_] - uf(h0_);                               \
            float l1_ = f_[2 * p_ + 1] - uf(h1_);                           \
            lv_[p_] = (fu(l1_) & 0xFFFF0000u) | (fu(l0_) >> 16);            \
        }                                                                   \
        AH = __builtin_bit_cast(short8, hv_);                               \
        AL = __builtin_bit_cast(short8, lv_);                               \
    } while (0)

// bias+relu+split+wave-private LDS transpose of one 16-row block
// (C-layout acc pair -> A-layout hi/lo fragments)
#define TRX(accLo, accHi, bcLo, bcHi, OUTH, OUTL)                           \
    do {                                                                    \
        _Pragma("unroll")                                                   \
        for (int i_ = 0; i_ < 4; ++i_) {                                    \
            int row_ = 4 * g + i_;                                          \
            float h_ = fmaxf((accLo)[i_] + (bcLo), 0.f);                    \
            unsigned hb_ = fu(h_) & 0xFFFF0000u;                            \
            hbuf[wave][0][row_][r16] = (unsigned short)(hb_ >> 16);         \
            hbuf[wave][1][row_][r16] = (unsigned short)(fu(h_ - uf(hb_)) >> 16); \
            float h2_ = fmaxf((accHi)[i_] + (bcHi), 0.f);                   \
            unsigned hb2_ = fu(h2_) & 0xFFFF0000u;                          \
            hbuf[wave][0][row_][16 + r16] = (unsigned short)(hb2_ >> 16);   \
            hbuf[wave][1][row_][16 + r16] = (unsigned short)(fu(h2_ - uf(hb2_)) >> 16); \
        }                                                                   \
        OUTH = *reinterpret_cast<const short8*>(&hbuf[wave][0][r16][g * 8]);\
        OUTL = *reinterpret_cast<const short8*>(&hbuf[wave][1][r16][g * 8]);\
    } while (0)

__global__ __launch_bounds__(256, 3) void gnn_mfma(
    const float* __restrict__ x, const unsigned short* __restrict__ wf,
    const float* __restrict__ b0, const float* __restrict__ b1,
    const float* __restrict__ b2, float* __restrict__ out,
    int n_tiles, int stride)
{
    __shared__ __align__(16) unsigned short wlds[N_CHUNKS * 512];  // 22 KB
    // wave-private transpose buffer: [wave][hl][row 16][col 32 + pad 8]
    __shared__ __align__(16) unsigned short hbuf[4][2][16][40];    // 10.25 KB

    const int tid  = threadIdx.x;
    const int wave = tid >> 6;
    const int l    = tid & 63;
    const int r16  = l & 15;
    const int g    = l >> 4;

    // ---- stage weight fragments into LDS once per block ----
    {
        const uint4v* wfv = reinterpret_cast<const uint4v*>(wf);
        uint4v* wl = reinterpret_cast<uint4v*>(wlds);
        for (int gg = tid; gg < WLDS_GRANULES; gg += 256)
            wl[gg] = wfv[gg];
    }
    __syncthreads();   // the only block-wide barrier

    const short8* WL = reinterpret_cast<const short8*>(wlds);

    const float bc0a = b0[r16], bc0b = b0[16 + r16];
    const float bc1a = b1[r16], bc1b = b1[16 + r16];
    const float bc2  = b2[r16];

    const int gw = blockIdx.x * 4 + wave;   // global wave id

    for (int tile = gw; tile < n_tiles; tile += stride) {
        const int nb = tile * 32;           // 32 nodes per wave-tile
        const float* xr0 = x + (size_t)(nb + r16) * N_IN + g * 8;
        const float* xr1 = xr0 + (size_t)16 * N_IN;

        // -------- layer 0: h0 = relu(x @ W0 + b0), K=128, 2 row-blocks ----
        f32x4 aA0 = {0.f, 0.f, 0.f, 0.f};
        f32x4 aA1 = {0.f, 0.f, 0.f, 0.f};
        f32x4 aB0 = {0.f, 0.f, 0.f, 0.f};
        f32x4 aB1 = {0.f, 0.f, 0.f, 0.f};

        #pragma unroll
        for (int kc = 0; kc < 4; ++kc) {
            f32x4 xa0 = __builtin_nontemporal_load(
                reinterpret_cast<const f32x4*>(xr0 + kc * 32));
            f32x4 xb0 = __builtin_nontemporal_load(
                reinterpret_cast<const f32x4*>(xr0 + kc * 32 + 4));
            f32x4 xa1 = __builtin_nontemporal_load(
                reinterpret_cast<const f32x4*>(xr1 + kc * 32));
            f32x4 xb1 = __builtin_nontemporal_load(
                reinterpret_cast<const f32x4*>(xr1 + kc * 32 + 4));
            short8 ah0, al0, ah1, al1;
            SPLIT8(xa0, xb0, ah0, al0);
            SPLIT8(xa1, xb1, ah1, al1);
            short8 wh0 = WL[(kc * 4 + 0) * 64 + l];
            short8 wl0 = WL[(kc * 4 + 1) * 64 + l];
            short8 wh1 = WL[(kc * 4 + 2) * 64 + l];
            short8 wl1 = WL[(kc * 4 + 3) * 64 + l];
            MFMA3(aA0, ah0, al0, wh0, wl0);
            MFMA3(aA1, ah0, al0, wh1, wl1);
            MFMA3(aB0, ah1, al1, wh0, wl0);
            MFMA3(aB1, ah1, al1, wh1, wl1);
        }

        // transpose both row-blocks (sequential reuse of wave-private hbuf)
        short8 h0hA, h0lA, h0hB, h0lB;
        TRX(aA0, aA1, bc0a, bc0b, h0hA, h0lA);
        TRX(aB0, aB1, bc0a, bc0b, h0hB, h0lB);

        // -------- layer 1: h1 = relu(h0 @ W1 + b1), K=32 --------
        f32x4 c0A = {0.f, 0.f, 0.f, 0.f};
        f32x4 c1A = {0.f, 0.f, 0.f, 0.f};
        f32x4 c0B = {0.f, 0.f, 0.f, 0.f};
        f32x4 c1B = {0.f, 0.f, 0.f, 0.f};
        {
            short8 w1h0 = WL[(16 + 0) * 64 + l];
            short8 w1l0 = WL[(16 + 1) * 64 + l];
            short8 w1h1 = WL[(16 + 2) * 64 + l];
            short8 w1l1 = WL[(16 + 3) * 64 + l];
            MFMA3(c0A, h0hA, h0lA, w1h0, w1l0);
            MFMA3(c1A, h0hA, h0lA, w1h1, w1l1);
            MFMA3(c0B, h0hB, h0lB, w1h0, w1l0);
            MFMA3(c1B, h0hB, h0lB, w1h1, w1l1);
        }
        short8 h1hA, h1lA, h1hB, h1lB;
        TRX(c0A, c1A, bc1a, bc1b, h1hA, h1lA);
        TRX(c0B, c1B, bc1a, bc1b, h1hB, h1lB);

        // -------- layer 2: o = h1 @ W2 + b2, K=32, N=16 --------
        f32x4 oA = {0.f, 0.f, 0.f, 0.f};
        f32x4 oB = {0.f, 0.f, 0.f, 0.f};
        {
            short8 w2h = WL[(20) * 64 + l];
            short8 w2l = WL[(21) * 64 + l];
            MFMA3(oA, h1hA, h1lA, w2h, w2l);
            MFMA3(oB, h1hB, h1lB, w2h, w2l);
        }
        #pragma unroll
        for (int i = 0; i < 4; ++i) {
            int row = 4 * g + i;
            __builtin_nontemporal_store(
                oA[i] + bc2, out + (size_t)(nb + row) * N_OUT + r16);
            __builtin_nontemporal_store(
                oB[i] + bc2, out + (size_t)(nb + 16 + row) * N_OUT + r16);
        }
    }
}

extern "C" void kernel_launch(void* const* d_in, const int* in_sizes, int n_in,
                              void* d_out, int out_size, void* d_ws, size_t ws_size,
                              hipStream_t stream) {
    // setup_inputs() order: x, edge_index, edge_weight, W0, b0, W1, b1, W2, b2
    const float* x  = (const float*)d_in[0];
    const float* W0 = (const float*)d_in[3];
    const float* b0 = (const float*)d_in[4];
    const float* W1 = (const float*)d_in[5];
    const float* b1 = (const float*)d_in[6];
    const float* W2 = (const float*)d_in[7];
    const float* b2 = (const float*)d_in[8];
    float* out = (float*)d_out;
    unsigned short* wf = (unsigned short*)d_ws;   // 22 KB of fragment data

    int n_nodes = in_sizes[0] / N_IN;             // 1,000,000
    int n_tiles = n_nodes / 32;                   // 31,250 (exact)

    split_weights<<<(TOTAL_WF_SHORTS + 255) / 256, 256, 0, stream>>>(W0, W1, W2, wf);

    const int n_blocks = 768;                     // 3 blocks/CU resident
    const int n_waves_total = n_blocks * 4;
    gnn_mfma<<<dim3(n_blocks), dim3(256), 0, stream>>>(
        x, wf, b0, b1, b2, out, n_tiles, n_waves_total);
}

// Round 9
// 113.557 us; speedup vs baseline: 1.0613x; 1.0613x over previous
//
#include <hip/hip_runtime.h>
#include <stdint.h>

// Fused 3-layer MLP via MFMA with split-bf16 (hi+lo) 3-term products:
//   out = relu(relu(x@W0+b0)@W1+b1)@W2+b2
// x: [N,128] f32, W0:[128,32], W1:[32,32], W2:[32,16], out:[N,16] f32.
// edge_index/edge_weight unused (ChebConv K=1).
//
// R9 = R7 compute structure + x staged via global_load_lds DMA:
//  - wave-private LDS double buffer (2 x 8KB/wave); prefetch next tile's
//    16x128 f32 block with 8 global_load_lds_dwordx4 (fire-and-forget,
//    vmcnt-tracked, no VGPR coupling) while computing current tile
//  - LDS dest is linear (HW constraint); bank-conflict-free fragment reads
//    via BOTH-SIDES swizzle (rule 21): source granule pre-swizzled
//    (t ^ row) per lane, read applies same XOR -> each 8-lane group hits
//    8 distinct bank-quads
//  - 1 block/CU (96KB LDS), 256 persistent blocks; latency hidden by the
//    DMA queue (32KB outstanding/CU), not TLP
//
// MFMA frag layouts (m89-verified):
//  A: lane l holds A[l&15][8*(l>>4)+j], j=0..7
//  B: lane l holds B[8*(l>>4)+j][l&15]
//  C/D: lane l holds D[4*(l>>4)+i][l&15], i=0..3
// Split: v = hi + lo, hi = trunc-to-bf16 (bit mask, exact),
// lo = rne-bf16(v - hi); product = ah*bh + al*bh + ah*bl (~f32 accuracy).

#define N_IN  128
#define HID   32
#define N_OUT 16

using f32x4  = __attribute__((ext_vector_type(4))) float;
using short8 = __attribute__((ext_vector_type(8))) short;
using uint4v = __attribute__((ext_vector_type(4))) unsigned int;

// chunk layout in ws (each chunk = 64 lanes * 8 bf16 = 512 shorts = 1KB):
//  W0: chunks [0,16): chunk = kc*4 + nh*2 + hl   (kc=0..3, nh=0..1, hl=0..1)
//  W1: chunks [16,20): 16 + nh*2 + hl
//  W2: chunks [20,22): 20 + hl
#define N_CHUNKS 22
#define TOTAL_WF_SHORTS (N_CHUNKS * 512)
#define WLDS_GRANULES (N_CHUNKS * 64)   // 16B granules

__device__ __forceinline__ unsigned fu(float f) {
    union { float f; unsigned u; } v; v.f = f; return v.u;
}
__device__ __forceinline__ float uf(unsigned u) {
    union { unsigned u; float f; } v; v.u = u; return v.f;
}
__device__ __forceinline__ unsigned short f2bf_rne(float f) {
    unsigned u = fu(f);
    return (unsigned short)((u + 0x7fffu + ((u >> 16) & 1u)) >> 16);
}

__global__ void split_weights(const float* __restrict__ W0,
                              const float* __restrict__ W1,
                              const float* __restrict__ W2,
                              unsigned short* __restrict__ wf) {
    int idx = blockIdx.x * blockDim.x + threadIdx.x;
    if (idx >= TOTAL_WF_SHORTS) return;
    int chunk  = idx >> 9;
    int within = idx & 511;
    int lane = within >> 3;
    int j    = within & 7;
    const float* W; int ncol, k, col, hl;
    if (chunk < 16) {
        int kc = chunk >> 2, nh = (chunk >> 1) & 1; hl = chunk & 1;
        k = kc * 32 + 8 * (lane >> 4) + j; col = nh * 16 + (lane & 15);
        W = W0; ncol = HID;
    } else if (chunk < 20) {
        int c2 = chunk - 16, nh = c2 >> 1; hl = c2 & 1;
        k = 8 * (lane >> 4) + j; col = nh * 16 + (lane & 15);
        W = W1; ncol = HID;
    } else {
        hl = chunk - 20;
        k = 8 * (lane >> 4) + j; col = lane & 15;
        W = W2; ncol = N_OUT;
    }
    float v = W[k * ncol + col];
    unsigned hi_bits = fu(v) & 0xFFFF0000u;
    wf[idx] = (hl == 0) ? (unsigned short)(hi_bits >> 16)
                        : f2bf_rne(v - uf(hi_bits));
}

#define MFMA3(acc, ah, al, bh, bl)                                          \
    do {                                                                    \
        acc = __builtin_amdgcn_mfma_f32_16x16x32_bf16(ah, bh, acc, 0, 0, 0);\
        acc = __builtin_amdgcn_mfma_f32_16x16x32_bf16(al, bh, acc, 0, 0, 0);\
        acc = __builtin_amdgcn_mfma_f32_16x16x32_bf16(ah, bl, acc, 0, 0, 0);\
    } while (0)

#define GAS1(p) ((const unsigned int __attribute__((address_space(1)))*)(uintptr_t)(p))
#define LAS3(p) ((unsigned int __attribute__((address_space(3)))*)(uintptr_t)(p))

__global__ __launch_bounds__(256, 1) void gnn_mfma(
    const float* __restrict__ x, const unsigned short* __restrict__ wf,
    const float* __restrict__ b0, const float* __restrict__ b1,
    const float* __restrict__ b2, float* __restrict__ out,
    int n_tiles, int stride)
{
    __shared__ __align__(16) unsigned short wlds[N_CHUNKS * 512];  // 22 KB
    // wave-private transpose buffer: [wave][hl][row 16][col 32 + pad 8]
    __shared__ __align__(16) unsigned short hbuf[4][2][16][40];    // 10.25 KB
    // wave-private x staging double-buffer: [wave][buf][16 rows x 128 f32]
    __shared__ __align__(16) float xbuf[4][2][2048];               // 64 KB

    const int tid  = threadIdx.x;
    const int wave = tid >> 6;
    const int l    = tid & 63;
    const int r16  = l & 15;
    const int g    = l >> 4;

    // ---- stage weight fragments into LDS once per block ----
    {
        const uint4v* wfv = reinterpret_cast<const uint4v*>(wf);
        uint4v* wl = reinterpret_cast<uint4v*>(wlds);
        for (int gg = tid; gg < WLDS_GRANULES; gg += 256)
            wl[gg] = wfv[gg];
    }
    __syncthreads();   // the only block-wide barrier

    const short8* WL = reinterpret_cast<const short8*>(wlds);

    const float bc0a = b0[r16], bc0b = b0[16 + r16];
    const float bc1a = b1[r16], bc1b = b1[16 + r16];
    const float bc2  = b2[r16];

    const int gw = blockIdx.x * 4 + wave;   // global wave id

    // staging geometry: instruction i writes LDS granules [i*64 + lane]
    // (linear, HW: base + lane*16B). LDS granule (row, t) must hold global
    // granule (row, t ^ row) -> per-lane source is the inverse-swizzled addr.
    const int srow = l >> 5;   // 0/1: row parity within instruction
    const int st   = l & 31;   // granule within row

    // stage one 16x128 f32 tile into xbuf[wave][buf] (8 x dwordx4 DMA)
    #define STAGE(buf, tileidx)                                                \
    do {                                                                       \
        const float* sb_ = x + (size_t)(tileidx) * 16 * N_IN;                  \
        _Pragma("unroll")                                                      \
        for (int i_ = 0; i_ < 8; ++i_) {                                       \
            int row_ = i_ * 2 + srow;                                          \
            const float* src_ = sb_ + row_ * N_IN + ((st ^ row_) << 2);        \
            float* dst_ = &xbuf[wave][buf][i_ * 256];                          \
            __builtin_amdgcn_global_load_lds(GAS1(src_), LAS3(dst_), 16, 0, 0);\
        }                                                                      \
    } while (0)

    int b = 0;
    STAGE(0, gw);   // prologue: first tile -> buf 0 (gw < n_tiles always)

    for (int tile = gw; tile < n_tiles; tile += stride) {
        const int nb = tile * 16;

        // wait for current buffer's DMA (and old stores) to land
        asm volatile("s_waitcnt vmcnt(0)" ::: "memory");
        __builtin_amdgcn_sched_barrier(0);

        // swizzled fragment reads: lane wants global granules (r16, t0), (r16, t0+1)
        f32x4 xa[4], xbv[4];
        {
            const f32x4* rb = reinterpret_cast<const f32x4*>(&xbuf[wave][b][r16 * 128]);
            #pragma unroll
            for (int kc = 0; kc < 4; ++kc) {
                int t0 = g * 2 + kc * 8;
                xa[kc]  = rb[t0 ^ r16];
                xbv[kc] = rb[(t0 + 1) ^ r16];
            }
        }

        // prefetch next tile into the other buffer (fire-and-forget)
        {
            int ntt = tile + stride;
            int pf = (ntt < n_tiles) ? ntt : tile;   // tail: restage self, never read
            STAGE(b ^ 1, pf);
        }

        // -------- layer 0: h0 = relu(x @ W0 + b0), K=128 --------
        f32x4 acc0 = {0.f, 0.f, 0.f, 0.f};
        f32x4 acc1 = {0.f, 0.f, 0.f, 0.f};

        #pragma unroll
        for (int kc = 0; kc < 4; ++kc) {
            float f[8] = {xa[kc][0], xa[kc][1], xa[kc][2], xa[kc][3],
                          xbv[kc][0], xbv[kc][1], xbv[kc][2], xbv[kc][3]};
            uint4v hv, lv;
            #pragma unroll
            for (int p = 0; p < 4; ++p) {
                unsigned u0 = fu(f[2 * p]), u1 = fu(f[2 * p + 1]);
                unsigned h0b = u0 & 0xFFFF0000u, h1b = u1 & 0xFFFF0000u;
                hv[p] = h1b | (u0 >> 16);
                float l0 = f[2 * p] - uf(h0b), l1 = f[2 * p + 1] - uf(h1b);
                lv[p] = (fu(l1) & 0xFFFF0000u) | (fu(l0) >> 16);
            }
            short8 ah = __builtin_bit_cast(short8, hv);
            short8 al = __builtin_bit_cast(short8, lv);
            short8 w0h0 = WL[(kc * 4 + 0) * 64 + l];
            short8 w0l0 = WL[(kc * 4 + 1) * 64 + l];
            short8 w0h1 = WL[(kc * 4 + 2) * 64 + l];
            short8 w0l1 = WL[(kc * 4 + 3) * 64 + l];
            MFMA3(acc0, ah, al, w0h0, w0l0);
            MFMA3(acc1, ah, al, w0h1, w0l1);
        }

        // bias + relu, split hi/lo, wave-private LDS transpose (no barrier)
        #pragma unroll
        for (int i = 0; i < 4; ++i) {
            int row = 4 * g + i;
            float h = fmaxf(acc0[i] + bc0a, 0.f);
            unsigned hb = fu(h) & 0xFFFF0000u;
            hbuf[wave][0][row][r16] = (unsigned short)(hb >> 16);
            hbuf[wave][1][row][r16] = (unsigned short)(fu(h - uf(hb)) >> 16);
            float h2 = fmaxf(acc1[i] + bc0b, 0.f);
            unsigned hb2 = fu(h2) & 0xFFFF0000u;
            hbuf[wave][0][row][16 + r16] = (unsigned short)(hb2 >> 16);
            hbuf[wave][1][row][16 + r16] = (unsigned short)(fu(h2 - uf(hb2)) >> 16);
        }
        short8 h0h = *reinterpret_cast<const short8*>(&hbuf[wave][0][r16][g * 8]);
        short8 h0l = *reinterpret_cast<const short8*>(&hbuf[wave][1][r16][g * 8]);

        // -------- layer 1: h1 = relu(h0 @ W1 + b1), K=32 --------
        f32x4 acc2 = {0.f, 0.f, 0.f, 0.f};
        f32x4 acc3 = {0.f, 0.f, 0.f, 0.f};
        {
            short8 w1h0 = WL[(16 + 0) * 64 + l];
            short8 w1l0 = WL[(16 + 1) * 64 + l];
            short8 w1h1 = WL[(16 + 2) * 64 + l];
            short8 w1l1 = WL[(16 + 3) * 64 + l];
            MFMA3(acc2, h0h, h0l, w1h0, w1l0);
            MFMA3(acc3, h0h, h0l, w1h1, w1l1);
        }
        #pragma unroll
        for (int i = 0; i < 4; ++i) {
            int row = 4 * g + i;
            float h = fmaxf(acc2[i] + bc1a, 0.f);
            unsigned hb = fu(h) & 0xFFFF0000u;
            hbuf[wave][0][row][r16] = (unsigned short)(hb >> 16);
            hbuf[wave][1][row][r16] = (unsigned short)(fu(h - uf(hb)) >> 16);
            float h2 = fmaxf(acc3[i] + bc1b, 0.f);
            unsigned hb2 = fu(h2) & 0xFFFF0000u;
            hbuf[wave][0][row][16 + r16] = (unsigned short)(hb2 >> 16);
            hbuf[wave][1][row][16 + r16] = (unsigned short)(fu(h2 - uf(hb2)) >> 16);
        }
        short8 h1h = *reinterpret_cast<const short8*>(&hbuf[wave][0][r16][g * 8]);
        short8 h1l = *reinterpret_cast<const short8*>(&hbuf[wave][1][r16][g * 8]);

        // -------- layer 2: o = h1 @ W2 + b2, K=32, N=16 --------
        f32x4 accO = {0.f, 0.f, 0.f, 0.f};
        {
            short8 w2h = WL[(20) * 64 + l];
            short8 w2l = WL[(21) * 64 + l];
            MFMA3(accO, h1h, h1l, w2h, w2l);
        }
        #pragma unroll
        for (int i = 0; i < 4; ++i) {
            int row = 4 * g + i;
            __builtin_nontemporal_store(
                accO[i] + bc2, out + (size_t)(nb + row) * N_OUT + r16);
        }

        b ^= 1;
    }
    #undef STAGE
}

extern "C" void kernel_launch(void* const* d_in, const int* in_sizes, int n_in,
                              void* d_out, int out_size, void* d_ws, size_t ws_size,
                              hipStream_t stream) {
    // setup_inputs() order: x, edge_index, edge_weight, W0, b0, W1, b1, W2, b2
    const float* x  = (const float*)d_in[0];
    const float* W0 = (const float*)d_in[3];
    const float* b0 = (const float*)d_in[4];
    const float* W1 = (const float*)d_in[5];
    const float* b1 = (const float*)d_in[6];
    const float* W2 = (const float*)d_in[7];
    const float* b2 = (const float*)d_in[8];
    float* out = (float*)d_out;
    unsigned short* wf = (unsigned short*)d_ws;   // 22 KB of fragment data

    int n_nodes = in_sizes[0] / N_IN;             // 1,000,000
    int n_tiles = n_nodes / 16;                   // 62,500 (exact)

    split_weights<<<(TOTAL_WF_SHORTS + 255) / 256, 256, 0, stream>>>(W0, W1, W2, wf);

    const int n_blocks = 256;                     // 1 block/CU (96KB LDS)
    const int n_waves_total = n_blocks * 4;       // 1024 waves
    gnn_mfma<<<dim3(n_blocks), dim3(256), 0, stream>>>(
        x, wf, b0, b1, b2, out, n_tiles, n_waves_total);
}